// Round 3
// baseline (124.810 us; speedup 1.0000x reference)
//
#include <hip/hip_runtime.h>
#include <hip/hip_bf16.h>

#define BATCH 64
#define SEQ 32
#define DIM 1024
#define EOUT 4096
#define NFW 16

#define BM 128   // rows per block tile (4 batch-slots x 32 seq)
#define BN 64    // cols per block tile
#define BK 64    // k chunk
#define LDS_K 68 // padded row stride in bf16 elements (136B)
#define MAX_ITEMS 28  // sum ceil(cnt/4) <= (64 + 3*16)/4 = 28

typedef float  f32x4 __attribute__((ext_vector_type(4)));
typedef short  s16x4 __attribute__((ext_vector_type(4)));
typedef short  s16x8 __attribute__((ext_vector_type(8)));

__device__ __forceinline__ short f2bf(float f) {
    union { float f; unsigned u; } v; v.f = f;
    unsigned r = v.u + 0x7fffu + ((v.u >> 16) & 1u);   // RNE
    return (short)(r >> 16);
}

// ---- planning kernel: build compact (fw, mg, nvalid) work list in ws ----
// ws[0] = n_items; ws[1+i] = (fw<<8) | (mg<<4) | nvalid
__global__ void qgen_plan(const int* __restrict__ fwv, int* __restrict__ ws) {
    const int tid = threadIdx.x;   // 64 threads
    const int v = fwv[tid];
    int nitems = 0;
    for (int fw = 0; fw < NFW; ++fw) {
        const unsigned long long m = __ballot(v == fw);
        if (tid == 0) {
            const int cnt = __popcll(m);
            for (int mg = 0; mg * 4 < cnt; ++mg) {
                const int nv = min(4, cnt - mg * 4);
                ws[1 + nitems] = (fw << 8) | (mg << 4) | nv;
                ++nitems;
            }
        }
    }
    if (tid == 0) ws[0] = nitems;
}

__global__ __launch_bounds__(256) void qgen_kernel(
    const float* __restrict__ x,      // [64][32][1024]
    const int*   __restrict__ fwv,    // [64]
    const float* __restrict__ w,      // [16][1024][4096]
    const float* __restrict__ bias,   // [16][4096]
    const int*   __restrict__ ws,     // work list
    float*       __restrict__ out)    // [64][32][4096] flat
{
    const int tid = threadIdx.x;

    // ---- early exit BEFORE any heavy loads ----
    const int nitems = ws[0];
    if ((int)blockIdx.y >= nitems) return;
    const int item   = ws[1 + blockIdx.y];
    const int myfw   = item >> 8;
    const int mg     = (item >> 4) & 15;
    const int nvalid = item & 15;
    const int n0     = blockIdx.x * BN;

    __shared__ int   s_list[BATCH];
    __shared__ short XT[BM][LDS_K];
    __shared__ short WT[BN][LDS_K];

    // ---- W staging map: (col wn, k-quarter wkq), column dword loads ----
    const int wn  = tid & 63;
    const int wkq = (tid >> 6) * 16;
    const float* wsrc = w + (long)myfw * DIM * EOUT + (long)wkq * EOUT + n0 + wn;

    // ---- prologue: issue W loads for chunk 0 immediately ----
    float wreg[16];
    #pragma unroll
    for (int j = 0; j < 16; ++j) wreg[j] = wsrc[(long)j * EOUT];

    // ---- rebuild batch list for this fw (wave 0 ballot + rank) ----
    if (tid < 64) {
        const int myv = fwv[tid];
        const unsigned long long mask = __ballot(myv == myfw);
        if (myv == myfw) {
            const int rank = __popcll(mask & ((1ull << tid) - 1ull));
            s_list[rank] = tid;
        }
    }
    __syncthreads();

    // ---- X staging map: (row sm, k-half skb) ----
    const int  sm    = tid >> 1;
    const int  skb   = (tid & 1) * 32;
    const int  sslot = sm >> 5;
    const bool svalid = (sslot < nvalid);
    const long sbatch = svalid ? s_list[mg * 4 + sslot] : 0;
    const float* xsrc = x + (sbatch * SEQ + (sm & 31)) * (long)DIM + skb;

    // ---- wave / fragment geometry: 2x2 waves, each 64 rows x 32 cols ----
    const int wave  = tid >> 6;
    const int lane  = tid & 63;
    const int wm    = (wave >> 1) * 64;   // wave row base
    const int wncol = (wave & 1) * 32;    // wave col base
    const int lrow  = lane & 15;
    const int lk    = (lane >> 4) * 4;

    f32x4 acc[4][2];
    #pragma unroll
    for (int i = 0; i < 4; ++i)
        #pragma unroll
        for (int j = 0; j < 2; ++j)
            acc[i][j] = (f32x4){0.f, 0.f, 0.f, 0.f};

    // zero-fill invalid X rows once
    if (!svalid) {
        s16x4 z = {0, 0, 0, 0};
        #pragma unroll
        for (int j = 0; j < 8; ++j) *(s16x4*)&XT[sm][skb + 4 * j] = z;
    }

    for (int k0 = 0; k0 < DIM; k0 += BK) {
        __syncthreads();   // previous compute done reading LDS

        // (1) issue X loads early — latency overlaps W cvt+write
        float4 xv[8];
        if (svalid) {
            const float* px = xsrc + k0;
            #pragma unroll
            for (int j = 0; j < 8; ++j) xv[j] = *(const float4*)(px + 4 * j);
        }

        // (2) W: cvt + ds_write (wreg landed during previous MFMA phase)
        #pragma unroll
        for (int j = 0; j < 4; ++j) {
            s16x4 p = { f2bf(wreg[4*j]), f2bf(wreg[4*j+1]),
                        f2bf(wreg[4*j+2]), f2bf(wreg[4*j+3]) };
            *(s16x4*)&WT[wn][wkq + 4 * j] = p;
        }

        // (3) issue W loads for next chunk (in flight across MFMA phase)
        {
            const long k1 = (k0 + BK < DIM) ? (long)(k0 + BK) : 0;
            const float* pw = wsrc + k1 * EOUT;
            #pragma unroll
            for (int j = 0; j < 16; ++j) wreg[j] = pw[(long)j * EOUT];
        }

        // (4) X: cvt + ds_write
        if (svalid) {
            #pragma unroll
            for (int j = 0; j < 8; ++j) {
                s16x4 p = { f2bf(xv[j].x), f2bf(xv[j].y),
                            f2bf(xv[j].z), f2bf(xv[j].w) };
                *(s16x4*)&XT[sm][skb + 4 * j] = p;
            }
        }

        __syncthreads();   // staging visible

        #pragma unroll
        for (int kk = 0; kk < BK; kk += 32) {
            s16x8 a[4], b[2];
            #pragma unroll
            for (int i = 0; i < 4; ++i) {
                const short* p = &XT[wm + i * 16 + lrow][kk + lk];
                s16x4 lo = *(const s16x4*)p;
                s16x4 hi = *(const s16x4*)(p + 16);
                a[i] = __builtin_shufflevector(lo, hi, 0, 1, 2, 3, 4, 5, 6, 7);
            }
            #pragma unroll
            for (int j = 0; j < 2; ++j) {
                const short* p = &WT[wncol + j * 16 + lrow][kk + lk];
                s16x4 lo = *(const s16x4*)p;
                s16x4 hi = *(const s16x4*)(p + 16);
                b[j] = __builtin_shufflevector(lo, hi, 0, 1, 2, 3, 4, 5, 6, 7);
            }
            #pragma unroll
            for (int i = 0; i < 4; ++i)
                #pragma unroll
                for (int j = 0; j < 2; ++j)
                    acc[i][j] = __builtin_amdgcn_mfma_f32_16x16x32_bf16(
                        a[i], b[j], acc[i][j], 0, 0, 0);
        }
    }

    // ---- epilogue: +bias, tanh, store ----
    int bidx[4];
    #pragma unroll
    for (int s = 0; s < 4; ++s) bidx[s] = (s < nvalid) ? s_list[mg * 4 + s] : -1;
    const float* bv = bias + (long)myfw * EOUT;

    #pragma unroll
    for (int i = 0; i < 4; ++i) {
        const int mbase = wm + i * 16 + (lane >> 4) * 4;
        #pragma unroll
        for (int j = 0; j < 2; ++j) {
            const int col = n0 + wncol + j * 16 + lrow;
            const float bb = bv[col];
            #pragma unroll
            for (int r = 0; r < 4; ++r) {
                const int m    = mbase + r;
                const int slot = m >> 5;
                const int b    = bidx[slot];
                if (b >= 0) {
                    float v = acc[i][j][r] + bb;
                    float e = __expf(2.0f * v);
                    float t = 1.0f - __fdividef(2.0f, e + 1.0f);
                    out[((long)(b * SEQ + (m & 31))) * EOUT + col] = t;
                }
            }
        }
    }
}

extern "C" void kernel_launch(void* const* d_in, const int* in_sizes, int n_in,
                              void* d_out, int out_size, void* d_ws, size_t ws_size,
                              hipStream_t stream) {
    const float* x    = (const float*)d_in[0];
    const int*   fwv  = (const int*)d_in[1];
    const float* w    = (const float*)d_in[2];
    const float* bias = (const float*)d_in[3];
    float* out = (float*)d_out;
    int*   ws  = (int*)d_ws;

    qgen_plan<<<1, 64, 0, stream>>>(fwv, ws);

    dim3 grid(EOUT / BN, MAX_ITEMS, 1);   // (64, 28)
    qgen_kernel<<<grid, 256, 0, stream>>>(x, fwv, w, bias, ws, out);
}

// Round 5
// 92.754 us; speedup vs baseline: 1.3456x; 1.3456x over previous
//
#include <hip/hip_runtime.h>
#include <hip/hip_bf16.h>

#define BATCH 64
#define SEQ 32
#define DIM 1024
#define EOUT 4096
#define NFW 16

#define BM 128   // rows per block tile (4 batch-slots x 32 seq)
#define BN 128   // cols per block tile
#define BK 64    // k chunk
#define XK 72    // XT row stride in bf16 elems (144B: 16B-aligned rows for b128)
#define WK 68    // WT row stride in bf16 elems (136B: conflict-free b64 reads)
#define MAX_ITEMS 28  // sum ceil(cnt/4) <= (64 + 3*16)/4 = 28

typedef float  f32x4 __attribute__((ext_vector_type(4)));
typedef short  s16x4 __attribute__((ext_vector_type(4)));
typedef short  s16x8 __attribute__((ext_vector_type(8)));

__device__ __forceinline__ short f2bf(float f) {
    union { float f; unsigned u; } v; v.f = f;
    unsigned r = v.u + 0x7fffu + ((v.u >> 16) & 1u);   // RNE
    return (short)(r >> 16);
}

// ---- X fp32 -> bf16 pre-convert (2M elems, 8 per thread) ----
__global__ __launch_bounds__(256) void qgen_convx(const float* __restrict__ x,
                                                  short* __restrict__ xbf) {
    const long i = ((long)blockIdx.x * 256 + threadIdx.x) * 8;
    float4 a = *(const float4*)(x + i);
    float4 b = *(const float4*)(x + i + 4);
    s16x8 p = { f2bf(a.x), f2bf(a.y), f2bf(a.z), f2bf(a.w),
                f2bf(b.x), f2bf(b.y), f2bf(b.z), f2bf(b.w) };
    *(s16x8*)(xbf + i) = p;
}

// ---- planning kernel: build compact (fw, mg, nvalid) work list ----
// ws[0] = n_items; ws[1+i] = (fw<<8) | (mg<<4) | nvalid
__global__ void qgen_plan(const int* __restrict__ fwv, int* __restrict__ ws) {
    const int tid = threadIdx.x;   // 64 threads
    const int v = fwv[tid];
    int nitems = 0;
    for (int fw = 0; fw < NFW; ++fw) {
        const unsigned long long m = __ballot(v == fw);
        if (tid == 0) {
            const int cnt = __popcll(m);
            for (int mg = 0; mg * 4 < cnt; ++mg) {
                const int nv = min(4, cnt - mg * 4);
                ws[1 + nitems] = (fw << 8) | (mg << 4) | nv;
                ++nitems;
            }
        }
    }
    if (tid == 0) ws[0] = nitems;
}

template<int XB>
__global__ __launch_bounds__(256) void qgen_kernel(
    const float* __restrict__ x,      // [64][32][1024] fp32
    const short* __restrict__ xbf,    // [64][32][1024] bf16 (if XB)
    const int*   __restrict__ fwv,    // [64]
    const float* __restrict__ w,      // [16][1024][4096]
    const float* __restrict__ bias,   // [16][4096]
    const int*   __restrict__ ws,     // work list
    float*       __restrict__ out)    // [64][32][4096] flat
{
    const int tid = threadIdx.x;

    // ---- early exit BEFORE any heavy loads ----
    const int nitems = ws[0];
    if ((int)blockIdx.y >= nitems) return;
    const int item   = ws[1 + blockIdx.y];
    const int myfw   = item >> 8;
    const int mg     = (item >> 4) & 15;
    const int nvalid = item & 15;
    const int n0     = blockIdx.x * BN;

    __shared__ int   s_list[BATCH];
    __shared__ short XT[BM][XK];
    __shared__ short WT[BN][WK];

    // ---- W staging map: (col wn, k-half wkh), column dword loads ----
    const int wn  = tid & 127;
    const int wkh = (tid >> 7) * 32;
    const float* wsrc = w + (long)myfw * DIM * EOUT + (long)wkh * EOUT + n0 + wn;

    // ---- prologue: issue W loads for chunk 0 immediately ----
    float wreg[32];
    #pragma unroll
    for (int j = 0; j < 32; ++j) wreg[j] = wsrc[(long)j * EOUT];

    // ---- rebuild batch list for this fw (wave 0 ballot + rank) ----
    if (tid < 64) {
        const int myv = fwv[tid];
        const unsigned long long mask = __ballot(myv == myfw);
        if (myv == myfw) {
            const int rank = __popcll(mask & ((1ull << tid) - 1ull));
            s_list[rank] = tid;
        }
    }
    __syncthreads();

    // ---- X staging map: (row sm, k-half skb: 32 elems each) ----
    const int  sm    = tid >> 1;
    const int  skb   = (tid & 1) * 32;
    const int  sslot = sm >> 5;
    const bool svalid = (sslot < nvalid);
    const long srow   = (svalid ? s_list[mg * 4 + sslot] : 0) * SEQ + (sm & 31);
    const float* xsrc32 = x   + srow * (long)DIM + skb;
    const short* xsrc16 = xbf + srow * (long)DIM + skb;

    // ---- wave / fragment geometry: 2x2 waves, each 64 rows x 64 cols ----
    const int wave  = tid >> 6;
    const int lane  = tid & 63;
    const int wm    = (wave >> 1) * 64;
    const int wncol = (wave & 1) * 64;
    const int lrow  = lane & 15;
    const int lk    = (lane >> 4) * 4;

    f32x4 acc[4][4];
    #pragma unroll
    for (int i = 0; i < 4; ++i)
        #pragma unroll
        for (int j = 0; j < 4; ++j)
            acc[i][j] = (f32x4){0.f, 0.f, 0.f, 0.f};

    // zero-fill invalid X rows once
    if (!svalid) {
        s16x4 z = {0, 0, 0, 0};
        #pragma unroll
        for (int j = 0; j < 8; ++j) *(s16x4*)&XT[sm][skb + 4 * j] = z;
    }

    for (int k0 = 0; k0 < DIM; k0 += BK) {
        __syncthreads();   // previous compute done reading LDS

        // (1) issue X loads early — latency overlaps W cvt+write
        s16x8  x16[4];       // 4 x 8 shorts = full 32-elem span
        float4 xv[8];
        if (XB) {
            if (svalid) {
                #pragma unroll
                for (int j = 0; j < 4; ++j)
                    x16[j] = *(const s16x8*)(xsrc16 + k0 + 8 * j);
            }
        } else {
            if (svalid) {
                const float* px = xsrc32 + k0;
                #pragma unroll
                for (int j = 0; j < 8; ++j) xv[j] = *(const float4*)(px + 4 * j);
            }
        }

        // (2) W: cvt + ds_write (wreg landed during previous MFMA phase)
        #pragma unroll
        for (int j = 0; j < 8; ++j) {
            s16x4 p = { f2bf(wreg[4*j]), f2bf(wreg[4*j+1]),
                        f2bf(wreg[4*j+2]), f2bf(wreg[4*j+3]) };
            *(s16x4*)&WT[wn][wkh + 4 * j] = p;
        }

        // (3) issue W loads for next chunk (in flight across MFMA phase)
        {
            const long k1 = (k0 + BK < DIM) ? (long)(k0 + BK) : 0;
            const float* pw = wsrc + k1 * EOUT;
            #pragma unroll
            for (int j = 0; j < 32; ++j) wreg[j] = pw[(long)j * EOUT];
        }

        // (4) X -> LDS
        if (svalid) {
            if (XB) {
                #pragma unroll
                for (int j = 0; j < 4; ++j)
                    *(s16x8*)&XT[sm][skb + 8 * j] = x16[j];
            } else {
                #pragma unroll
                for (int j = 0; j < 8; ++j) {
                    s16x4 p = { f2bf(xv[j].x), f2bf(xv[j].y),
                                f2bf(xv[j].z), f2bf(xv[j].w) };
                    *(s16x4*)&XT[sm][skb + 4 * j] = p;
                }
            }
        }

        __syncthreads();   // staging visible

        #pragma unroll
        for (int kk = 0; kk < BK; kk += 32) {
            s16x8 a[4], b[4];
            #pragma unroll
            for (int i = 0; i < 4; ++i) {
                const short* p = &XT[wm + i * 16 + lrow][kk + lk];
                s16x4 lo = *(const s16x4*)p;
                s16x4 hi = *(const s16x4*)(p + 16);
                a[i] = __builtin_shufflevector(lo, hi, 0, 1, 2, 3, 4, 5, 6, 7);
            }
            #pragma unroll
            for (int j = 0; j < 4; ++j) {
                const short* p = &WT[wncol + j * 16 + lrow][kk + lk];
                s16x4 lo = *(const s16x4*)p;
                s16x4 hi = *(const s16x4*)(p + 16);
                b[j] = __builtin_shufflevector(lo, hi, 0, 1, 2, 3, 4, 5, 6, 7);
            }
            #pragma unroll
            for (int i = 0; i < 4; ++i)
                #pragma unroll
                for (int j = 0; j < 4; ++j)
                    acc[i][j] = __builtin_amdgcn_mfma_f32_16x16x32_bf16(
                        a[i], b[j], acc[i][j], 0, 0, 0);
        }
    }

    // ---- epilogue: +bias, tanh, store ----
    int bidx[4];
    #pragma unroll
    for (int s = 0; s < 4; ++s) bidx[s] = (s < nvalid) ? s_list[mg * 4 + s] : -1;
    const float* bv = bias + (long)myfw * EOUT;

    #pragma unroll
    for (int i = 0; i < 4; ++i) {
        const int mbase = wm + i * 16 + (lane >> 4) * 4;
        #pragma unroll
        for (int j = 0; j < 4; ++j) {
            const int col = n0 + wncol + j * 16 + lrow;
            const float bb = bv[col];
            #pragma unroll
            for (int r = 0; r < 4; ++r) {
                const int m    = mbase + r;
                const int slot = m >> 5;
                const int b    = bidx[slot];
                if (b >= 0) {
                    float v = acc[i][j][r] + bb;
                    float e = __expf(2.0f * v);
                    float t = 1.0f - __fdividef(2.0f, e + 1.0f);
                    out[((long)(b * SEQ + (m & 31))) * EOUT + col] = t;
                }
            }
        }
    }
}

extern "C" void kernel_launch(void* const* d_in, const int* in_sizes, int n_in,
                              void* d_out, int out_size, void* d_ws, size_t ws_size,
                              hipStream_t stream) {
    const float* x    = (const float*)d_in[0];
    const int*   fwv  = (const int*)d_in[1];
    const float* w    = (const float*)d_in[2];
    const float* bias = (const float*)d_in[3];
    float* out = (float*)d_out;
    int*   ws  = (int*)d_ws;
    short* xbf = (short*)((char*)d_ws + 256);

    const size_t need = 256 + (size_t)BATCH * SEQ * DIM * 2;

    qgen_plan<<<1, 64, 0, stream>>>(fwv, ws);

    dim3 grid(EOUT / BN, MAX_ITEMS, 1);   // (32, 28)
    if (ws_size >= need) {
        qgen_convx<<<(BATCH * SEQ * DIM) / (256 * 8), 256, 0, stream>>>(x, xbf);
        qgen_kernel<1><<<grid, 256, 0, stream>>>(x, xbf, fwv, w, bias, ws, out);
    } else {
        qgen_kernel<0><<<grid, 256, 0, stream>>>(x, xbf, fwv, w, bias, ws, out);
    }
}

// Round 6
// 84.086 us; speedup vs baseline: 1.4843x; 1.1031x over previous
//
#include <hip/hip_runtime.h>
#include <hip/hip_bf16.h>

#define BATCH 64
#define SEQ 32
#define DIM 1024
#define EOUT 4096
#define NFW 16

#define BM 256   // rows per block tile (8 batch-slots x 32 seq)
#define BN 128   // cols per block tile
#define BK 64    // k chunk
#define XK 72    // XT row stride in bf16 elems (144B: 16B-aligned rows)
#define WK 68    // WT row stride in bf16 elems (136B: conflict-free b64 reads)
#define MAX_ITEMS 22  // max sum ceil(cnt/8) with sum cnt = 64 over 16 fws

typedef float  f32x4 __attribute__((ext_vector_type(4)));
typedef short  s16x4 __attribute__((ext_vector_type(4)));
typedef short  s16x8 __attribute__((ext_vector_type(8)));

__device__ __forceinline__ short f2bf(float f) {
    union { float f; unsigned u; } v; v.f = f;
    unsigned r = v.u + 0x7fffu + ((v.u >> 16) & 1u);   // RNE
    return (short)(r >> 16);
}

// ---- fused prep: X fp32->bf16 convert (all blocks) + plan (block 0) ----
// ws[0] = n_items; ws[1+i] = (fw<<8) | (mg<<4) | nvalid
__global__ __launch_bounds__(256) void qgen_prep(const float* __restrict__ x,
                                                 short* __restrict__ xbf,
                                                 const int* __restrict__ fwv,
                                                 int* __restrict__ ws) {
    const int tid = threadIdx.x;
    if (blockIdx.x == 0 && tid < 64) {
        const int v = fwv[tid];
        int nitems = 0;
        for (int fw = 0; fw < NFW; ++fw) {
            const unsigned long long m = __ballot(v == fw);
            if (tid == 0) {
                const int cnt = __popcll(m);
                for (int mg = 0; mg * 8 < cnt; ++mg) {
                    const int nv = min(8, cnt - mg * 8);
                    ws[1 + nitems] = (fw << 8) | (mg << 4) | nv;
                    ++nitems;
                }
            }
        }
        if (tid == 0) ws[0] = nitems;
    }
    const long i = ((long)blockIdx.x * 256 + tid) * 8;
    float4 a = *(const float4*)(x + i);
    float4 b = *(const float4*)(x + i + 4);
    s16x8 p = { f2bf(a.x), f2bf(a.y), f2bf(a.z), f2bf(a.w),
                f2bf(b.x), f2bf(b.y), f2bf(b.z), f2bf(b.w) };
    *(s16x8*)(xbf + i) = p;
}

// ---- standalone plan (fp32 fallback path, no convert) ----
__global__ void qgen_plan(const int* __restrict__ fwv, int* __restrict__ ws) {
    const int tid = threadIdx.x;   // 64 threads
    const int v = fwv[tid];
    int nitems = 0;
    for (int fw = 0; fw < NFW; ++fw) {
        const unsigned long long m = __ballot(v == fw);
        if (tid == 0) {
            const int cnt = __popcll(m);
            for (int mg = 0; mg * 8 < cnt; ++mg) {
                const int nv = min(8, cnt - mg * 8);
                ws[1 + nitems] = (fw << 8) | (mg << 4) | nv;
                ++nitems;
            }
        }
    }
    if (tid == 0) ws[0] = nitems;
}

template<int XB>
__global__ __launch_bounds__(512) void qgen_kernel(
    const float* __restrict__ x,      // [64][32][1024] fp32
    const short* __restrict__ xbf,    // [64][32][1024] bf16 (if XB)
    const int*   __restrict__ fwv,    // [64]
    const float* __restrict__ w,      // [16][1024][4096]
    const float* __restrict__ bias,   // [16][4096]
    const int*   __restrict__ ws,     // work list
    float*       __restrict__ out)    // [64][32][4096] flat
{
    const int tid = threadIdx.x;

    // ---- early exit BEFORE any heavy loads ----
    const int nitems = ws[0];
    if ((int)blockIdx.y >= nitems) return;
    const int item   = ws[1 + blockIdx.y];
    const int myfw   = item >> 8;
    const int mg     = (item >> 4) & 15;
    const int nvalid = item & 15;         // 1..8
    const int n0     = blockIdx.x * BN;

    __shared__ int   s_list[BATCH];
    __shared__ short XT[BM][XK];
    __shared__ short WT[BN][WK];

    // ---- W staging map: (col wn, k-16th wkh), column dword loads ----
    const int wn  = tid & 127;
    const int wkh = (tid >> 7) * 16;      // 4 groups x 16 k-rows
    const float* wsrc = w + (long)myfw * DIM * EOUT + (long)wkh * EOUT + n0 + wn;

    // ---- prologue: issue W loads for chunk 0 immediately ----
    float wreg[16];
    #pragma unroll
    for (int j = 0; j < 16; ++j) wreg[j] = wsrc[(long)j * EOUT];

    // ---- rebuild batch list for this fw (wave 0 ballot + rank) ----
    if (tid < 64) {
        const int myv = fwv[tid];
        const unsigned long long mask = __ballot(myv == myfw);
        if (myv == myfw) {
            const int rank = __popcll(mask & ((1ull << tid) - 1ull));
            s_list[rank] = tid;
        }
    }
    __syncthreads();

    // ---- X staging map: (row sm 0..255, k-half skb: 32 elems) ----
    const int  sm    = tid >> 1;
    const int  skb   = (tid & 1) * 32;
    const int  sslot = sm >> 5;           // 0..7
    const bool svalid = (sslot < nvalid);
    const long srow   = (svalid ? s_list[mg * 8 + sslot] : 0) * SEQ + (sm & 31);
    const float* xsrc32 = x   + srow * (long)DIM + skb;
    const short* xsrc16 = xbf + srow * (long)DIM + skb;

    // ---- wave / fragment geometry: 4x2 waves, each 64 rows x 64 cols ----
    const int wave  = tid >> 6;           // 0..7
    const int lane  = tid & 63;
    const int wm    = (wave >> 1) * 64;   // 0,64,128,192
    const int wncol = (wave & 1) * 64;    // 0,64
    const int lrow  = lane & 15;
    const int lk    = (lane >> 4) * 4;

    f32x4 acc[4][4];
    #pragma unroll
    for (int i = 0; i < 4; ++i)
        #pragma unroll
        for (int j = 0; j < 4; ++j)
            acc[i][j] = (f32x4){0.f, 0.f, 0.f, 0.f};

    // zero-fill invalid X rows once
    if (!svalid) {
        s16x4 z = {0, 0, 0, 0};
        #pragma unroll
        for (int j = 0; j < 8; ++j) *(s16x4*)&XT[sm][skb + 4 * j] = z;
    }

    for (int k0 = 0; k0 < DIM; k0 += BK) {
        __syncthreads();   // previous compute done reading LDS

        // (1) issue X loads early — latency overlaps W cvt+write
        s16x8  x16[4];
        float4 xv[8];
        if (XB) {
            if (svalid) {
                #pragma unroll
                for (int j = 0; j < 4; ++j)
                    x16[j] = *(const s16x8*)(xsrc16 + k0 + 8 * j);
            }
        } else {
            if (svalid) {
                const float* px = xsrc32 + k0;
                #pragma unroll
                for (int j = 0; j < 8; ++j) xv[j] = *(const float4*)(px + 4 * j);
            }
        }

        // (2) W: cvt + ds_write (wreg landed during previous MFMA phase)
        #pragma unroll
        for (int j = 0; j < 4; ++j) {
            s16x4 p = { f2bf(wreg[4*j]), f2bf(wreg[4*j+1]),
                        f2bf(wreg[4*j+2]), f2bf(wreg[4*j+3]) };
            *(s16x4*)&WT[wn][wkh + 4 * j] = p;
        }

        // (3) issue W loads for next chunk (in flight across MFMA phase)
        {
            const long k1 = (k0 + BK < DIM) ? (long)(k0 + BK) : 0;
            const float* pw = wsrc + k1 * EOUT;
            #pragma unroll
            for (int j = 0; j < 16; ++j) wreg[j] = pw[(long)j * EOUT];
        }

        // (4) X -> LDS
        if (svalid) {
            if (XB) {
                #pragma unroll
                for (int j = 0; j < 4; ++j)
                    *(s16x8*)&XT[sm][skb + 8 * j] = x16[j];
            } else {
                #pragma unroll
                for (int j = 0; j < 8; ++j) {
                    s16x4 p = { f2bf(xv[j].x), f2bf(xv[j].y),
                                f2bf(xv[j].z), f2bf(xv[j].w) };
                    *(s16x4*)&XT[sm][skb + 4 * j] = p;
                }
            }
        }

        __syncthreads();   // staging visible

        #pragma unroll
        for (int kk = 0; kk < BK; kk += 32) {
            s16x8 a[4], b[4];
            #pragma unroll
            for (int i = 0; i < 4; ++i) {
                const short* p = &XT[wm + i * 16 + lrow][kk + lk];
                s16x4 lo = *(const s16x4*)p;
                s16x4 hi = *(const s16x4*)(p + 16);
                a[i] = __builtin_shufflevector(lo, hi, 0, 1, 2, 3, 4, 5, 6, 7);
            }
            #pragma unroll
            for (int j = 0; j < 4; ++j) {
                const short* p = &WT[wncol + j * 16 + lrow][kk + lk];
                s16x4 lo = *(const s16x4*)p;
                s16x4 hi = *(const s16x4*)(p + 16);
                b[j] = __builtin_shufflevector(lo, hi, 0, 1, 2, 3, 4, 5, 6, 7);
            }
            #pragma unroll
            for (int i = 0; i < 4; ++i)
                #pragma unroll
                for (int j = 0; j < 4; ++j)
                    acc[i][j] = __builtin_amdgcn_mfma_f32_16x16x32_bf16(
                        a[i], b[j], acc[i][j], 0, 0, 0);
        }
    }

    // ---- epilogue: +bias, tanh, store ----
    int bidx[8];
    #pragma unroll
    for (int s = 0; s < 8; ++s) bidx[s] = (s < nvalid) ? s_list[mg * 8 + s] : -1;
    const float* bv = bias + (long)myfw * EOUT;

    #pragma unroll
    for (int i = 0; i < 4; ++i) {
        const int mbase = wm + i * 16 + (lane >> 4) * 4;
        #pragma unroll
        for (int j = 0; j < 4; ++j) {
            const int col = n0 + wncol + j * 16 + lrow;
            const float bb = bv[col];
            #pragma unroll
            for (int r = 0; r < 4; ++r) {
                const int m    = mbase + r;
                const int slot = m >> 5;
                const int b    = bidx[slot];
                if (b >= 0) {
                    float v = acc[i][j][r] + bb;
                    float e = __expf(2.0f * v);
                    float t = 1.0f - __fdividef(2.0f, e + 1.0f);
                    out[((long)(b * SEQ + (m & 31))) * EOUT + col] = t;
                }
            }
        }
    }
}

extern "C" void kernel_launch(void* const* d_in, const int* in_sizes, int n_in,
                              void* d_out, int out_size, void* d_ws, size_t ws_size,
                              hipStream_t stream) {
    const float* x    = (const float*)d_in[0];
    const int*   fwv  = (const int*)d_in[1];
    const float* w    = (const float*)d_in[2];
    const float* bias = (const float*)d_in[3];
    float* out = (float*)d_out;
    int*   ws  = (int*)d_ws;
    short* xbf = (short*)((char*)d_ws + 256);

    const size_t need = 256 + (size_t)BATCH * SEQ * DIM * 2;

    dim3 grid(EOUT / BN, MAX_ITEMS, 1);   // (32, 22)
    if (ws_size >= need) {
        qgen_prep<<<(BATCH * SEQ * DIM) / (256 * 8), 256, 0, stream>>>(x, xbf, fwv, ws);
        qgen_kernel<1><<<grid, 512, 0, stream>>>(x, xbf, fwv, w, bias, ws, out);
    } else {
        qgen_plan<<<1, 64, 0, stream>>>(fwv, ws);
        qgen_kernel<0><<<grid, 512, 0, stream>>>(x, xbf, fwv, w, bias, ws, out);
    }
}

// Round 7
// 83.445 us; speedup vs baseline: 1.4957x; 1.0077x over previous
//
#include <hip/hip_runtime.h>
#include <hip/hip_bf16.h>

#define BATCH 64
#define SEQ 32
#define DIM 1024
#define EOUT 4096
#define NFW 16

#define BM 256   // rows per block tile (8 batch-slots x 32 seq)
#define BN 128   // cols per block tile
#define BK 64    // k chunk
#define XK 68    // XT row stride: 17 dwords, odd -> conflict-free b64 ops (R3-proven)
#define WK 68    // WT row stride: same
#define MAX_ITEMS 22  // max sum ceil(cnt/8) with sum cnt = 64 over 16 fws

typedef float  f32x4 __attribute__((ext_vector_type(4)));
typedef short  s16x4 __attribute__((ext_vector_type(4)));
typedef short  s16x8 __attribute__((ext_vector_type(8)));

__device__ __forceinline__ short f2bf(float f) {
    union { float f; unsigned u; } v; v.f = f;
    unsigned r = v.u + 0x7fffu + ((v.u >> 16) & 1u);   // RNE
    return (short)(r >> 16);
}

// ---- fused prep: X fp32->bf16 convert (all blocks) + plan (block 0) ----
// ws[0] = n_items; ws[1+i] = (fw<<8) | (mg<<4) | nvalid
__global__ __launch_bounds__(256) void qgen_prep(const float* __restrict__ x,
                                                 short* __restrict__ xbf,
                                                 const int* __restrict__ fwv,
                                                 int* __restrict__ ws) {
    const int tid = threadIdx.x;
    if (blockIdx.x == 0 && tid < 64) {
        const int v = fwv[tid];
        int nitems = 0;
        for (int fw = 0; fw < NFW; ++fw) {
            const unsigned long long m = __ballot(v == fw);
            if (tid == 0) {
                const int cnt = __popcll(m);
                for (int mg = 0; mg * 8 < cnt; ++mg) {
                    const int nv = min(8, cnt - mg * 8);
                    ws[1 + nitems] = (fw << 8) | (mg << 4) | nv;
                    ++nitems;
                }
            }
        }
        if (tid == 0) ws[0] = nitems;
    }
    const long i = ((long)blockIdx.x * 256 + tid) * 8;
    float4 a = *(const float4*)(x + i);
    float4 b = *(const float4*)(x + i + 4);
    s16x8 p = { f2bf(a.x), f2bf(a.y), f2bf(a.z), f2bf(a.w),
                f2bf(b.x), f2bf(b.y), f2bf(b.z), f2bf(b.w) };
    *(s16x8*)(xbf + i) = p;
}

// ---- standalone plan (fp32 fallback path, no convert) ----
__global__ void qgen_plan(const int* __restrict__ fwv, int* __restrict__ ws) {
    const int tid = threadIdx.x;   // 64 threads
    const int v = fwv[tid];
    int nitems = 0;
    for (int fw = 0; fw < NFW; ++fw) {
        const unsigned long long m = __ballot(v == fw);
        if (tid == 0) {
            const int cnt = __popcll(m);
            for (int mg = 0; mg * 8 < cnt; ++mg) {
                const int nv = min(8, cnt - mg * 8);
                ws[1 + nitems] = (fw << 8) | (mg << 4) | nv;
                ++nitems;
            }
        }
    }
    if (tid == 0) ws[0] = nitems;
}

template<int XB>
__global__ __launch_bounds__(512) void qgen_kernel(
    const float* __restrict__ x,      // [64][32][1024] fp32
    const short* __restrict__ xbf,    // [64][32][1024] bf16 (if XB)
    const int*   __restrict__ fwv,    // [64]
    const float* __restrict__ w,      // [16][1024][4096]
    const float* __restrict__ bias,   // [16][4096]
    const int*   __restrict__ ws,     // work list
    float*       __restrict__ out)    // [64][32][4096] flat
{
    const int tid = threadIdx.x;

    // ---- early exit BEFORE any heavy loads ----
    const int nitems = ws[0];
    if ((int)blockIdx.y >= nitems) return;
    const int item   = ws[1 + blockIdx.y];
    const int myfw   = item >> 8;
    const int mg     = (item >> 4) & 15;
    const int nvalid = item & 15;         // 1..8
    const int n0     = blockIdx.x * BN;

    __shared__ int   s_list[BATCH];
    __shared__ short XT[BM][XK];
    __shared__ short WT[BN][WK];

    // ---- W staging map: (col wn, k-16th wkh), column dword loads ----
    const int wn  = tid & 127;
    const int wkh = (tid >> 7) * 16;      // 4 groups x 16 k-rows
    const float* wsrc = w + (long)myfw * DIM * EOUT + (long)wkh * EOUT + n0 + wn;

    // ---- prologue: issue W loads for chunk 0 immediately ----
    float wreg[16];
    #pragma unroll
    for (int j = 0; j < 16; ++j) wreg[j] = wsrc[(long)j * EOUT];

    // ---- rebuild batch list for this fw (wave 0 ballot + rank) ----
    if (tid < 64) {
        const int myv = fwv[tid];
        const unsigned long long mask = __ballot(myv == myfw);
        if (myv == myfw) {
            const int rank = __popcll(mask & ((1ull << tid) - 1ull));
            s_list[rank] = tid;
        }
    }
    __syncthreads();

    // ---- X staging map: (row sm 0..255, k-half skb: 32 elems) ----
    const int  sm    = tid >> 1;
    const int  skb   = (tid & 1) * 32;
    const int  sslot = sm >> 5;           // 0..7
    const bool svalid = (sslot < nvalid);
    const long srow   = (svalid ? s_list[mg * 8 + sslot] : 0) * SEQ + (sm & 31);
    const float* xsrc32 = x   + srow * (long)DIM + skb;
    const short* xsrc16 = xbf + srow * (long)DIM + skb;

    // ---- prologue: issue X loads for chunk 0 ----
    s16x8  x16[4];
    float4 xv[8];
    if (XB) {
        if (svalid) {
            #pragma unroll
            for (int j = 0; j < 4; ++j)
                x16[j] = *(const s16x8*)(xsrc16 + 8 * j);
        }
    } else {
        if (svalid) {
            #pragma unroll
            for (int j = 0; j < 8; ++j) xv[j] = *(const float4*)(xsrc32 + 4 * j);
        }
    }

    // ---- wave / fragment geometry: 4x2 waves, each 64 rows x 64 cols ----
    const int wave  = tid >> 6;           // 0..7
    const int lane  = tid & 63;
    const int wm    = (wave >> 1) * 64;   // 0,64,128,192
    const int wncol = (wave & 1) * 64;    // 0,64
    const int lrow  = lane & 15;
    const int lk    = (lane >> 4) * 4;

    f32x4 acc[4][4];
    #pragma unroll
    for (int i = 0; i < 4; ++i)
        #pragma unroll
        for (int j = 0; j < 4; ++j)
            acc[i][j] = (f32x4){0.f, 0.f, 0.f, 0.f};

    // zero-fill invalid X rows once
    if (!svalid) {
        s16x4 z = {0, 0, 0, 0};
        #pragma unroll
        for (int j = 0; j < 8; ++j) *(s16x4*)&XT[sm][skb + 4 * j] = z;
    }

    for (int k0 = 0; k0 < DIM; k0 += BK) {
        __syncthreads();   // previous compute done reading LDS

        // (1) X -> LDS (regs prefetched a full iteration ago); b64 stores only
        if (svalid) {
            if (XB) {
                #pragma unroll
                for (int j = 0; j < 4; ++j) {
                    s16x4 lo = __builtin_shufflevector(x16[j], x16[j], 0, 1, 2, 3);
                    s16x4 hi = __builtin_shufflevector(x16[j], x16[j], 4, 5, 6, 7);
                    *(s16x4*)&XT[sm][skb + 8 * j]     = lo;
                    *(s16x4*)&XT[sm][skb + 8 * j + 4] = hi;
                }
            } else {
                #pragma unroll
                for (int j = 0; j < 8; ++j) {
                    s16x4 p = { f2bf(xv[j].x), f2bf(xv[j].y),
                                f2bf(xv[j].z), f2bf(xv[j].w) };
                    *(s16x4*)&XT[sm][skb + 4 * j] = p;
                }
            }
        }

        // (2) W: cvt + ds_write (wreg landed during previous MFMA phase)
        #pragma unroll
        for (int j = 0; j < 4; ++j) {
            s16x4 p = { f2bf(wreg[4*j]), f2bf(wreg[4*j+1]),
                        f2bf(wreg[4*j+2]), f2bf(wreg[4*j+3]) };
            *(s16x4*)&WT[wn][wkh + 4 * j] = p;
        }

        // (3) issue W + X loads for next chunk (in flight across MFMA phase)
        {
            const long k1 = (k0 + BK < DIM) ? (long)(k0 + BK) : 0;
            const float* pw = wsrc + k1 * EOUT;
            #pragma unroll
            for (int j = 0; j < 16; ++j) wreg[j] = pw[(long)j * EOUT];
            if (XB) {
                if (svalid) {
                    #pragma unroll
                    for (int j = 0; j < 4; ++j)
                        x16[j] = *(const s16x8*)(xsrc16 + k1 + 8 * j);
                }
            } else {
                if (svalid) {
                    const float* px = xsrc32 + k1;
                    #pragma unroll
                    for (int j = 0; j < 8; ++j) xv[j] = *(const float4*)(px + 4 * j);
                }
            }
        }

        __syncthreads();   // staging visible

        #pragma unroll
        for (int kk = 0; kk < BK; kk += 32) {
            s16x8 a[4], b[4];
            #pragma unroll
            for (int i = 0; i < 4; ++i) {
                const short* p = &XT[wm + i * 16 + lrow][kk + lk];
                s16x4 lo = *(const s16x4*)p;
                s16x4 hi = *(const s16x4*)(p + 16);
                a[i] = __builtin_shufflevector(lo, hi, 0, 1, 2, 3, 4, 5, 6, 7);
            }
            #pragma unroll
            for (int j = 0; j < 4; ++j) {
                const short* p = &WT[wncol + j * 16 + lrow][kk + lk];
                s16x4 lo = *(const s16x4*)p;
                s16x4 hi = *(const s16x4*)(p + 16);
                b[j] = __builtin_shufflevector(lo, hi, 0, 1, 2, 3, 4, 5, 6, 7);
            }
            #pragma unroll
            for (int i = 0; i < 4; ++i)
                #pragma unroll
                for (int j = 0; j < 4; ++j)
                    acc[i][j] = __builtin_amdgcn_mfma_f32_16x16x32_bf16(
                        a[i], b[j], acc[i][j], 0, 0, 0);
        }
    }

    // ---- epilogue: +bias, tanh, store ----
    int bidx[8];
    #pragma unroll
    for (int s = 0; s < 8; ++s) bidx[s] = (s < nvalid) ? s_list[mg * 8 + s] : -1;
    const float* bv = bias + (long)myfw * EOUT;

    #pragma unroll
    for (int i = 0; i < 4; ++i) {
        const int mbase = wm + i * 16 + (lane >> 4) * 4;
        #pragma unroll
        for (int j = 0; j < 4; ++j) {
            const int col = n0 + wncol + j * 16 + lrow;
            const float bb = bv[col];
            #pragma unroll
            for (int r = 0; r < 4; ++r) {
                const int m    = mbase + r;
                const int slot = m >> 5;
                const int b    = bidx[slot];
                if (b >= 0) {
                    float v = acc[i][j][r] + bb;
                    float e = __expf(2.0f * v);
                    float t = 1.0f - __fdividef(2.0f, e + 1.0f);
                    out[((long)(b * SEQ + (m & 31))) * EOUT + col] = t;
                }
            }
        }
    }
}

extern "C" void kernel_launch(void* const* d_in, const int* in_sizes, int n_in,
                              void* d_out, int out_size, void* d_ws, size_t ws_size,
                              hipStream_t stream) {
    const float* x    = (const float*)d_in[0];
    const int*   fwv  = (const int*)d_in[1];
    const float* w    = (const float*)d_in[2];
    const float* bias = (const float*)d_in[3];
    float* out = (float*)d_out;
    int*   ws  = (int*)d_ws;
    short* xbf = (short*)((char*)d_ws + 256);

    const size_t need = 256 + (size_t)BATCH * SEQ * DIM * 2;

    dim3 grid(EOUT / BN, MAX_ITEMS, 1);   // (32, 22)
    if (ws_size >= need) {
        qgen_prep<<<(BATCH * SEQ * DIM) / (256 * 8), 256, 0, stream>>>(x, xbf, fwv, ws);
        qgen_kernel<1><<<grid, 512, 0, stream>>>(x, xbf, fwv, w, bias, ws, out);
    } else {
        qgen_plan<<<1, 64, 0, stream>>>(fwv, ws);
        qgen_kernel<0><<<grid, 512, 0, stream>>>(x, xbf, fwv, w, bias, ws, out);
    }
}